// Round 8
// baseline (38.073 us; speedup 1.0000x reference)
//
#include <hip/hip_runtime.h>
#include <stdint.h>

typedef __attribute__((ext_vector_type(8))) short short8;
typedef __attribute__((ext_vector_type(4))) float f32x4;
typedef __attribute__((ext_vector_type(4))) unsigned int u32x4;

#define NE 500000
#define NN 50000
#define NTILES 3125
#define MLP_BLOCKS 391       // ceil(3125 / 8 waves)
#define SC_BLOCKS 2048
#define SC_THREADS (SC_BLOCKS * 256)

__device__ __forceinline__ unsigned int f2bf1(float f) {
  unsigned int u = __builtin_bit_cast(unsigned int, f);
  u += 0x7FFFu + ((u >> 16) & 1u);   // round-to-nearest-even
  return u >> 16;
}
__device__ __forceinline__ unsigned int packbf2(float lo, float hi) {
  return f2bf1(lo) | (f2bf1(hi) << 16);
}
__device__ __forceinline__ short8 pack8(f32x4 a, f32x4 b) {
  short8 r;
  r[0] = (short)f2bf1(a[0]); r[1] = (short)f2bf1(a[1]);
  r[2] = (short)f2bf1(a[2]); r[3] = (short)f2bf1(a[3]);
  r[4] = (short)f2bf1(b[0]); r[5] = (short)f2bf1(b[1]);
  r[6] = (short)f2bf1(b[2]); r[7] = (short)f2bf1(b[3]);
  return r;
}

// ---------------------------------------------------------------------------
// Prep: repack W1..W4 (f32) into bf16 MFMA fragments (pi-relabeled for K=128
// layers so inter-layer transitions stay in registers).
// Frags [0,8)=W1 std, [8,40)=W2, [40,72)=W3, [72,136)=W4.
// ---------------------------------------------------------------------------
__global__ __launch_bounds__(256) void prep_weights(
    const float* __restrict__ W1, const float* __restrict__ W2,
    const float* __restrict__ W3, const float* __restrict__ W4,
    unsigned short* __restrict__ wf) {
  int idx = blockIdx.x * 256 + threadIdx.x;
  if (idx >= 8704) return;
  int f = idx >> 6, l = idx & 63;
  int c2 = l & 15, g = l >> 4;
  const float *pa, *pb;
  if (f < 8) {                       // W1: standard slot layout (K=32)
    const float* base = W1 + (f * 16 + c2) * 32 + g * 8;
    pa = base; pb = base + 4;
  } else {                           // W2/W3/W4: pi-relabeled (K=128)
    const float* W; int i2, kfq, nb;
    if (f < 40)      { W = W2; i2 = f - 8;  kfq = i2 >> 3; nb = i2 & 7;  }
    else if (f < 72) { W = W3; i2 = f - 40; kfq = i2 >> 3; nb = i2 & 7;  }
    else             { W = W4; i2 = f - 72; kfq = i2 >> 4; nb = i2 & 15; }
    const float* base = W + (nb * 16 + c2) * 128 + g * 4;
    pa = base + kfq * 16;            // j=0..3  -> k = kfq*16 + g*4 + j
    pb = base + (kfq + 4) * 16;      // j=4..7  -> k = (kfq+4)*16 + g*4 + (j-4)
  }
  f32x4 x0 = *(const f32x4*)pa;
  f32x4 x1 = *(const f32x4*)pb;
  *(short8*)&wf[f * 512 + l * 8] = pack8(x0, x1);
}

// ---------------------------------------------------------------------------
// MLP: 512 threads = 8 waves/block, ONE 16-node tile per wave (3125 waves,
// grid 391). LDS holds only W1..W3 (72 KB) + biases -> 2 blocks/CU;
// single-tile register footprint (~110 VGPR) + __launch_bounds__(512,4)
// -> 4 waves/SIMD (2x latency hiding vs R7's 2/SIMD at 160 VGPR).
// W4 fragments read from global (L2-resident, coalesced 1KB/instr).
// k-relabel keeps all layer transitions in registers.
// ---------------------------------------------------------------------------
__global__ __launch_bounds__(512, 4) void mlp_kernel(
    const float* __restrict__ ef, const float* __restrict__ nfeat,
    const float* __restrict__ b1, const float* __restrict__ b2,
    const float* __restrict__ b3, const float* __restrict__ b4,
    const unsigned short* __restrict__ wf, float* __restrict__ Rout) {
  __shared__ __align__(16) unsigned short wlds[36864];   // 72 KB: W1..W3 frags
  __shared__ __align__(16) float blds[640];              // b1|b2|b3|b4

  const int t = threadIdx.x;
  const int lane = t & 63, w = t >> 6;
  const int l15 = lane & 15, lg = lane >> 4;
  const int tile = blockIdx.x * 8 + w;
  const int n0 = (tile < NTILES ? tile : 0) * 16;

  // hoist ef loads: global latency overlaps the LDS staging below
  // (rows n0+l15 <= 50047 < 500000 -> always in-bounds)
  const float* xp = ef + (n0 + l15) * 32 + lg * 8;
  f32x4 x0 = *(const f32x4*)xp;
  f32x4 x1 = *(const f32x4*)(xp + 4);

  // ---- stage W1..W3 fragments (4608 x 16B) + biases
  {
    const u32x4* src = (const u32x4*)wf;
    u32x4* dst = (u32x4*)wlds;
    #pragma unroll
    for (int i = 0; i < 9; ++i) dst[t + i * 512] = src[t + i * 512];
  }
  if (t < 160) {
    const float* s = t < 32 ? b1 + t * 4
                   : t < 64 ? b2 + (t - 32) * 4
                   : t < 96 ? b3 + (t - 64) * 4
                   :          b4 + (t - 96) * 4;
    ((f32x4*)blds)[t] = *(const f32x4*)s;
  }
  __syncthreads();

  if (tile >= NTILES) return;

  // ReLU + pack C-layout acc into next-layer A-fragments (pure registers)
  auto transition = [&](const f32x4* a, short8* af) {
    unsigned int pk[8][2];
    #pragma unroll
    for (int nb = 0; nb < 8; ++nb) {
      pk[nb][0] = packbf2(fmaxf(a[nb][0], 0.f), fmaxf(a[nb][1], 0.f));
      pk[nb][1] = packbf2(fmaxf(a[nb][2], 0.f), fmaxf(a[nb][3], 0.f));
    }
    #pragma unroll
    for (int kf = 0; kf < 4; ++kf) {
      u32x4 u = { pk[kf][0], pk[kf][1], pk[kf + 4][0], pk[kf + 4][1] };
      af[kf] = __builtin_bit_cast(short8, u);
    }
  };

  // ---- layer 1: D = W1(A) x X^T(B), standard slots
  short8 a1 = pack8(x0, x1);
  f32x4 acc[8];
  #pragma unroll
  for (int nb = 0; nb < 8; ++nb) {
    f32x4 c0 = *(const f32x4*)&blds[nb * 16 + lg * 4];
    short8 wv = *(const short8*)&wlds[nb * 512 + lane * 8];
    acc[nb] = __builtin_amdgcn_mfma_f32_16x16x32_bf16(wv, a1, c0, 0, 0, 0);
  }
  short8 af[4];
  transition(acc, af);

  // ---- layers 2 and 3 (pi-relabeled weights from LDS)
  #pragma unroll
  for (int L = 0; L < 2; ++L) {
    const int wbase = 8 + L * 32, bbase = 128 + L * 128;
    #pragma unroll
    for (int nb = 0; nb < 8; ++nb) {
      f32x4 c = *(const f32x4*)&blds[bbase + nb * 16 + lg * 4];
      #pragma unroll
      for (int kf = 0; kf < 4; ++kf) {
        short8 wv = *(const short8*)&wlds[(wbase + kf * 8 + nb) * 512 + lane * 8];
        c = __builtin_amdgcn_mfma_f32_16x16x32_bf16(wv, af[kf], c, 0, 0, 0);
      }
      acc[nb] = c;
    }
    transition(acc, af);
  }

  // ---- layer 4 (pi-relabeled weights from GLOBAL/L2) + einsum epilogue
  const short8* w4 = (const short8*)(wf + 72 * 512);   // frag f' = kf*16+nb
  f32x4 nfv = *(const f32x4*)(nfeat + (n0 + l15) * 16 + lg * 4);
  float o0 = 0.f, o1 = 0.f, o2 = 0.f, o3 = 0.f;
  #pragma unroll
  for (int nb = 0; nb < 16; ++nb) {
    f32x4 d = *(const f32x4*)&blds[384 + nb * 16 + lg * 4];
    #pragma unroll
    for (int kf = 0; kf < 4; ++kf) {
      short8 wv = w4[(kf * 16 + nb) * 64 + lane];
      d = __builtin_amdgcn_mfma_f32_16x16x32_bf16(wv, af[kf], d, 0, 0, 0);
    }
    // lane holds H4[m=l15][c=nb*16+lg*4+r]; j = lg*4+r, i = nb
    float p = d[0]*nfv[0] + d[1]*nfv[1] + d[2]*nfv[2] + d[3]*nfv[3];
    p += __shfl_xor(p, 16, 64);
    p += __shfl_xor(p, 32, 64);
    int rs = nb - lg * 4;
    o0 = (rs == 0) ? p : o0; o1 = (rs == 1) ? p : o1;
    o2 = (rs == 2) ? p : o2; o3 = (rs == 3) ? p : o3;
  }
  f32x4 o = { o0, o1, o2, o3 };
  *(f32x4*)(Rout + (n0 + l15) * 16 + lg * 4) = o;
}

// ---------------------------------------------------------------------------
// Scatter: out[e] = R[edge_index[e,1]]. 4 lanes/edge, 16B/lane, plain stores,
// 4 independent items per thread for memory-level parallelism (R6-proven).
// ---------------------------------------------------------------------------
__global__ __launch_bounds__(256) void scatter_kernel(
    const int* __restrict__ eidx, const float* __restrict__ Rbuf,
    float* __restrict__ out) {
  const int tid = blockIdx.x * 256 + threadIdx.x;
  const int total = NE * 4;
  const int i0 = tid;
  const int i1 = tid + SC_THREADS;
  const int i2 = tid + 2 * SC_THREADS;
  const int i3 = tid + 3 * SC_THREADS;
  const bool d3 = (i3 < total);          // i0..i2 always valid

  int nA = eidx[((i0 >> 2) << 1) + 1];
  int nB = eidx[((i1 >> 2) << 1) + 1];
  int nC = eidx[((i2 >> 2) << 1) + 1];
  int nD = d3 ? eidx[((i3 >> 2) << 1) + 1] : 0;

  f32x4 vA = *(const f32x4*)(Rbuf + nA * 16 + (i0 & 3) * 4);
  f32x4 vB = *(const f32x4*)(Rbuf + nB * 16 + (i1 & 3) * 4);
  f32x4 vC = *(const f32x4*)(Rbuf + nC * 16 + (i2 & 3) * 4);
  f32x4 vD = d3 ? *(const f32x4*)(Rbuf + nD * 16 + (i3 & 3) * 4) : f32x4{0,0,0,0};

  *(f32x4*)(out + (size_t)i0 * 4) = vA;
  *(f32x4*)(out + (size_t)i1 * 4) = vB;
  *(f32x4*)(out + (size_t)i2 * 4) = vC;
  if (d3) *(f32x4*)(out + (size_t)i3 * 4) = vD;
}

extern "C" void kernel_launch(void* const* d_in, const int* in_sizes, int n_in,
                              void* d_out, int out_size, void* d_ws, size_t ws_size,
                              hipStream_t stream) {
  const float* ef = (const float*)d_in[0];
  const float* nf = (const float*)d_in[1];
  const float* W1 = (const float*)d_in[2];
  const float* b1 = (const float*)d_in[3];
  const float* W2 = (const float*)d_in[4];
  const float* b2 = (const float*)d_in[5];
  const float* W3 = (const float*)d_in[6];
  const float* b3 = (const float*)d_in[7];
  const float* W4 = (const float*)d_in[8];
  const float* b4 = (const float*)d_in[9];
  const int* eidx = (const int*)d_in[10];

  unsigned short* wfrag = (unsigned short*)d_ws;          // 139264 B bf16 frags
  float* Rbuf = (float*)((char*)d_ws + 139264);           // NN*16 f32 = 3.2 MB
  float* out = (float*)d_out;

  hipLaunchKernelGGL(prep_weights, dim3(34), dim3(256), 0, stream,
                     W1, W2, W3, W4, wfrag);
  hipLaunchKernelGGL(mlp_kernel, dim3(MLP_BLOCKS), dim3(512), 0, stream,
                     ef, nf, b1, b2, b3, b4, wfrag, Rbuf);
  hipLaunchKernelGGL(scatter_kernel, dim3(SC_BLOCKS), dim3(256), 0, stream,
                     eidx, Rbuf, out);
}

// Round 9
// 36.249 us; speedup vs baseline: 1.0503x; 1.0503x over previous
//
#include <hip/hip_runtime.h>
#include <stdint.h>

typedef __attribute__((ext_vector_type(8))) short short8;
typedef __attribute__((ext_vector_type(4))) float f32x4;
typedef __attribute__((ext_vector_type(4))) unsigned int u32x4;

#define NE 500000
#define NN 50000
#define NTILES 3125
#define MLP_BLOCKS 196       // 196 blocks x 16 waves = 3136 >= 3125 tiles
#define SC_BLOCKS 2048
#define SC_THREADS (SC_BLOCKS * 256)

__device__ __forceinline__ unsigned int f2bf1(float f) {
  unsigned int u = __builtin_bit_cast(unsigned int, f);
  u += 0x7FFFu + ((u >> 16) & 1u);   // round-to-nearest-even
  return u >> 16;
}
__device__ __forceinline__ unsigned int packbf2(float lo, float hi) {
  return f2bf1(lo) | (f2bf1(hi) << 16);
}
__device__ __forceinline__ short8 pack8(f32x4 a, f32x4 b) {
  short8 r;
  r[0] = (short)f2bf1(a[0]); r[1] = (short)f2bf1(a[1]);
  r[2] = (short)f2bf1(a[2]); r[3] = (short)f2bf1(a[3]);
  r[4] = (short)f2bf1(b[0]); r[5] = (short)f2bf1(b[1]);
  r[6] = (short)f2bf1(b[2]); r[7] = (short)f2bf1(b[3]);
  return r;
}

// ---------------------------------------------------------------------------
// Prep: repack W1..W4 (f32) into bf16 MFMA fragments (pi-relabeled for K=128
// layers so inter-layer transitions stay in registers).
// Frags [0,8)=W1 std, [8,40)=W2, [40,72)=W3, [72,136)=W4.
// ---------------------------------------------------------------------------
__global__ __launch_bounds__(256) void prep_weights(
    const float* __restrict__ W1, const float* __restrict__ W2,
    const float* __restrict__ W3, const float* __restrict__ W4,
    unsigned short* __restrict__ wf) {
  int idx = blockIdx.x * 256 + threadIdx.x;
  if (idx >= 8704) return;
  int f = idx >> 6, l = idx & 63;
  int c2 = l & 15, g = l >> 4;
  const float *pa, *pb;
  if (f < 8) {                       // W1: standard slot layout (K=32)
    const float* base = W1 + (f * 16 + c2) * 32 + g * 8;
    pa = base; pb = base + 4;
  } else {                           // W2/W3/W4: pi-relabeled (K=128)
    const float* W; int i2, kfq, nb;
    if (f < 40)      { W = W2; i2 = f - 8;  kfq = i2 >> 3; nb = i2 & 7;  }
    else if (f < 72) { W = W3; i2 = f - 40; kfq = i2 >> 3; nb = i2 & 7;  }
    else             { W = W4; i2 = f - 72; kfq = i2 >> 4; nb = i2 & 15; }
    const float* base = W + (nb * 16 + c2) * 128 + g * 4;
    pa = base + kfq * 16;            // j=0..3  -> k = kfq*16 + g*4 + j
    pb = base + (kfq + 4) * 16;      // j=4..7  -> k = (kfq+4)*16 + g*4 + (j-4)
  }
  f32x4 x0 = *(const f32x4*)pa;
  f32x4 x1 = *(const f32x4*)pb;
  *(short8*)&wf[f * 512 + l * 8] = pack8(x0, x1);
}

// ---------------------------------------------------------------------------
// MLP: 1024 threads = 16 waves/block, ONE 16-node tile per wave, ALL weights
// (W1..W4, 136 KB) in LDS. 1 block/CU; (1024,4) -> true 4 waves/SIMD with a
// lean ~100-reg body (acc 32 + af 16 + misc; no global loads in L4, so no
// prefetch register balloon -> no spill). Grid 196 = one staging per 16 tiles.
// k-relabel keeps all layer transitions in registers.
// ---------------------------------------------------------------------------
__global__ __launch_bounds__(1024, 4) void mlp_kernel(
    const float* __restrict__ ef, const float* __restrict__ nfeat,
    const float* __restrict__ b1, const float* __restrict__ b2,
    const float* __restrict__ b3, const float* __restrict__ b4,
    const unsigned short* __restrict__ wf, float* __restrict__ Rout) {
  __shared__ __align__(16) unsigned short wlds[69632];   // 136 KB: all frags
  __shared__ __align__(16) float blds[640];              // b1|b2|b3|b4

  const int t = threadIdx.x;
  const int lane = t & 63, w = t >> 6;
  const int l15 = lane & 15, lg = lane >> 4;
  const int tile = blockIdx.x * 16 + w;
  const int n0 = (tile < NTILES ? tile : 0) * 16;

  // hoist ef loads: global latency overlaps the LDS staging below
  const float* xp = ef + (n0 + l15) * 32 + lg * 8;
  f32x4 x0 = *(const f32x4*)xp;
  f32x4 x1 = *(const f32x4*)(xp + 4);

  // ---- stage all weight fragments (8704 x 16B) + biases
  {
    const u32x4* src = (const u32x4*)wf;
    u32x4* dst = (u32x4*)wlds;
    #pragma unroll
    for (int i = 0; i < 9; ++i) {
      int idx = t + i * 1024;
      if (idx < 8704) dst[idx] = src[idx];
    }
  }
  if (t < 160) {
    const float* s = t < 32 ? b1 + t * 4
                   : t < 64 ? b2 + (t - 32) * 4
                   : t < 96 ? b3 + (t - 64) * 4
                   :          b4 + (t - 96) * 4;
    ((f32x4*)blds)[t] = *(const f32x4*)s;
  }
  __syncthreads();

  if (tile >= NTILES) return;

  // ReLU + pack C-layout acc into next-layer A-fragments (pure registers)
  auto transition = [&](const f32x4* a, short8* af) {
    unsigned int pk[8][2];
    #pragma unroll
    for (int nb = 0; nb < 8; ++nb) {
      pk[nb][0] = packbf2(fmaxf(a[nb][0], 0.f), fmaxf(a[nb][1], 0.f));
      pk[nb][1] = packbf2(fmaxf(a[nb][2], 0.f), fmaxf(a[nb][3], 0.f));
    }
    #pragma unroll
    for (int kf = 0; kf < 4; ++kf) {
      u32x4 u = { pk[kf][0], pk[kf][1], pk[kf + 4][0], pk[kf + 4][1] };
      af[kf] = __builtin_bit_cast(short8, u);
    }
  };

  // ---- layer 1: D = W1(A) x X^T(B), standard slots
  short8 a1 = pack8(x0, x1);
  f32x4 acc[8];
  #pragma unroll
  for (int nb = 0; nb < 8; ++nb) {
    f32x4 c0 = *(const f32x4*)&blds[nb * 16 + lg * 4];
    short8 wv = *(const short8*)&wlds[nb * 512 + lane * 8];
    acc[nb] = __builtin_amdgcn_mfma_f32_16x16x32_bf16(wv, a1, c0, 0, 0, 0);
  }
  short8 af[4];
  transition(acc, af);

  // ---- layers 2 and 3 (pi-relabeled weights from LDS)
  #pragma unroll
  for (int L = 0; L < 2; ++L) {
    const int wbase = 8 + L * 32, bbase = 128 + L * 128;
    #pragma unroll
    for (int nb = 0; nb < 8; ++nb) {
      f32x4 c = *(const f32x4*)&blds[bbase + nb * 16 + lg * 4];
      #pragma unroll
      for (int kf = 0; kf < 4; ++kf) {
        short8 wv = *(const short8*)&wlds[(wbase + kf * 8 + nb) * 512 + lane * 8];
        c = __builtin_amdgcn_mfma_f32_16x16x32_bf16(wv, af[kf], c, 0, 0, 0);
      }
      acc[nb] = c;
    }
    transition(acc, af);
  }

  // ---- layer 4 (weights from LDS) + einsum epilogue
  // partial unroll: no nb-indexed arrays here, bounds register pressure
  f32x4 nfv = *(const f32x4*)(nfeat + (n0 + l15) * 16 + lg * 4);
  float o0 = 0.f, o1 = 0.f, o2 = 0.f, o3 = 0.f;
  #pragma unroll 4
  for (int nb = 0; nb < 16; ++nb) {
    f32x4 d = *(const f32x4*)&blds[384 + nb * 16 + lg * 4];
    #pragma unroll
    for (int kf = 0; kf < 4; ++kf) {
      short8 wv = *(const short8*)&wlds[(72 + kf * 16 + nb) * 512 + lane * 8];
      d = __builtin_amdgcn_mfma_f32_16x16x32_bf16(wv, af[kf], d, 0, 0, 0);
    }
    // lane holds H4[m=l15][c=nb*16+lg*4+r]; j = lg*4+r, i = nb
    float p = d[0]*nfv[0] + d[1]*nfv[1] + d[2]*nfv[2] + d[3]*nfv[3];
    p += __shfl_xor(p, 16, 64);
    p += __shfl_xor(p, 32, 64);
    int rs = nb - lg * 4;
    o0 = (rs == 0) ? p : o0; o1 = (rs == 1) ? p : o1;
    o2 = (rs == 2) ? p : o2; o3 = (rs == 3) ? p : o3;
  }
  f32x4 o = { o0, o1, o2, o3 };
  *(f32x4*)(Rout + (n0 + l15) * 16 + lg * 4) = o;
}

// ---------------------------------------------------------------------------
// Scatter: out[e] = R[edge_index[e,1]]. 4 lanes/edge, 16B/lane, plain stores,
// 4 independent items per thread for memory-level parallelism (R6-proven).
// ---------------------------------------------------------------------------
__global__ __launch_bounds__(256) void scatter_kernel(
    const int* __restrict__ eidx, const float* __restrict__ Rbuf,
    float* __restrict__ out) {
  const int tid = blockIdx.x * 256 + threadIdx.x;
  const int total = NE * 4;
  const int i0 = tid;
  const int i1 = tid + SC_THREADS;
  const int i2 = tid + 2 * SC_THREADS;
  const int i3 = tid + 3 * SC_THREADS;
  const bool d3 = (i3 < total);          // i0..i2 always valid

  int nA = eidx[((i0 >> 2) << 1) + 1];
  int nB = eidx[((i1 >> 2) << 1) + 1];
  int nC = eidx[((i2 >> 2) << 1) + 1];
  int nD = d3 ? eidx[((i3 >> 2) << 1) + 1] : 0;

  f32x4 vA = *(const f32x4*)(Rbuf + nA * 16 + (i0 & 3) * 4);
  f32x4 vB = *(const f32x4*)(Rbuf + nB * 16 + (i1 & 3) * 4);
  f32x4 vC = *(const f32x4*)(Rbuf + nC * 16 + (i2 & 3) * 4);
  f32x4 vD = d3 ? *(const f32x4*)(Rbuf + nD * 16 + (i3 & 3) * 4) : f32x4{0,0,0,0};

  *(f32x4*)(out + (size_t)i0 * 4) = vA;
  *(f32x4*)(out + (size_t)i1 * 4) = vB;
  *(f32x4*)(out + (size_t)i2 * 4) = vC;
  if (d3) *(f32x4*)(out + (size_t)i3 * 4) = vD;
}

extern "C" void kernel_launch(void* const* d_in, const int* in_sizes, int n_in,
                              void* d_out, int out_size, void* d_ws, size_t ws_size,
                              hipStream_t stream) {
  const float* ef = (const float*)d_in[0];
  const float* nf = (const float*)d_in[1];
  const float* W1 = (const float*)d_in[2];
  const float* b1 = (const float*)d_in[3];
  const float* W2 = (const float*)d_in[4];
  const float* b2 = (const float*)d_in[5];
  const float* W3 = (const float*)d_in[6];
  const float* b3 = (const float*)d_in[7];
  const float* W4 = (const float*)d_in[8];
  const float* b4 = (const float*)d_in[9];
  const int* eidx = (const int*)d_in[10];

  unsigned short* wfrag = (unsigned short*)d_ws;          // 139264 B bf16 frags
  float* Rbuf = (float*)((char*)d_ws + 139264);           // NN*16 f32 = 3.2 MB
  float* out = (float*)d_out;

  hipLaunchKernelGGL(prep_weights, dim3(34), dim3(256), 0, stream,
                     W1, W2, W3, W4, wfrag);
  hipLaunchKernelGGL(mlp_kernel, dim3(MLP_BLOCKS), dim3(1024), 0, stream,
                     ef, nf, b1, b2, b3, b4, wfrag, Rbuf);
  hipLaunchKernelGGL(scatter_kernel, dim3(SC_BLOCKS), dim3(256), 0, stream,
                     eidx, Rbuf, out);
}